// Round 2
// baseline (42036.163 us; speedup 1.0000x reference)
//
#include <hip/hip_runtime.h>
#include <cstdint>
#include <cstddef>

#define NT 2048   // timesteps
#define NB 64     // batch
#define NH 256    // hidden
#define NG 768    // 3*NH
#define NL 3      // layers
#define CHUNK 128 // timesteps per chunk
#define NCH (NT / CHUNK)

__device__ __forceinline__ float sigf(float x) {
    return 1.0f / (1.0f + __expf(-x));
}
__device__ __forceinline__ float tanhfast(float x) {
    // tanh(x) = 1 - 2/(exp(2x)+1); saturates correctly at +/-inf
    float e = __expf(2.0f * x);
    return 1.0f - 2.0f / (e + 1.0f);
}

// ---------------------------------------------------------------------------
// Repack W_hh[l][g][k] (row-major [3][768][256]) -> W4[l][kq][g][4]
// so that in the scan, lane j reads a contiguous float4 = W_hh[g][4kq..4kq+3].
// ---------------------------------------------------------------------------
__global__ void repack_whh(const float* __restrict__ whh, float* __restrict__ w4) {
    int idx = blockIdx.x * 256 + threadIdx.x;      // total 3*64*768*4 = 589824
    if (idx >= NL * 64 * NG * 4) return;
    int i  = idx & 3;
    int t1 = idx >> 2;
    int g  = t1 % NG;
    int t2 = t1 / NG;
    int kq = t2 & 63;
    int l  = t2 >> 6;
    w4[idx] = whh[((size_t)l * NG + g) * NH + (kq << 2) + i];
}

// ---------------------------------------------------------------------------
// C[M,768] = A[M,256] @ W[768,256]^T + bias   (fp32, LDS-tiled 64x64x32)
// grid: (768/64, M/64), block: 256 threads, each thread 4x4 outputs
// ---------------------------------------------------------------------------
__global__ __launch_bounds__(256) void gemm_gi(const float* __restrict__ A,
                                               const float* __restrict__ W,
                                               const float* __restrict__ bias,
                                               float* __restrict__ C) {
    __shared__ float As[32][68];   // [k][m], padded
    __shared__ float Bs[32][68];   // [k][n], padded
    const int tid = threadIdx.x;
    const int tx = tid & 15;
    const int ty = tid >> 4;
    const int m0 = blockIdx.y << 6;
    const int n0 = blockIdx.x << 6;
    const int lr = tid >> 2;        // 0..63 tile row for loading
    const int lc = tid & 3;         // 0..3

    float acc[4][4] = {{0.0f}};

    for (int kt = 0; kt < 256; kt += 32) {
#pragma unroll
        for (int h = 0; h < 2; ++h) {
            const int c = lc + (h << 2);            // 0..7 (float4 column)
            float4 av = *(const float4*)&A[(size_t)(m0 + lr) * 256 + kt + (c << 2)];
            float4 bv = *(const float4*)&W[(size_t)(n0 + lr) * 256 + kt + (c << 2)];
            As[(c << 2) + 0][lr] = av.x; As[(c << 2) + 1][lr] = av.y;
            As[(c << 2) + 2][lr] = av.z; As[(c << 2) + 3][lr] = av.w;
            Bs[(c << 2) + 0][lr] = bv.x; Bs[(c << 2) + 1][lr] = bv.y;
            Bs[(c << 2) + 2][lr] = bv.z; Bs[(c << 2) + 3][lr] = bv.w;
        }
        __syncthreads();
#pragma unroll
        for (int kk = 0; kk < 32; ++kk) {
            float4 a4 = *(const float4*)&As[kk][ty << 2];
            float4 b4 = *(const float4*)&Bs[kk][tx << 2];
            float a[4] = {a4.x, a4.y, a4.z, a4.w};
            float b[4] = {b4.x, b4.y, b4.z, b4.w};
#pragma unroll
            for (int i = 0; i < 4; ++i)
#pragma unroll
                for (int j = 0; j < 4; ++j)
                    acc[i][j] = fmaf(a[i], b[j], acc[i][j]);
        }
        __syncthreads();
    }

    const float4 bv = *(const float4*)&bias[n0 + (tx << 2)];
#pragma unroll
    for (int i = 0; i < 4; ++i) {
        float4 o;
        o.x = acc[i][0] + bv.x;
        o.y = acc[i][1] + bv.y;
        o.z = acc[i][2] + bv.z;
        o.w = acc[i][3] + bv.w;
        *(float4*)&C[(size_t)(m0 + (ty << 2) + i) * NG + n0 + (tx << 2)] = o;
    }
}

// ---------------------------------------------------------------------------
// GRU scan for `steps` timesteps of one layer (one chunk). One block per
// batch element; thread j owns h[j]. State persists in hstate[b*NH+j].
// gi: [steps,B,768] input gates (+b_ih). w4: [64][768][4] repacked W_hh.
// bh: [768]. outf: [steps,B,256] chunk outputs (or null). outl: [B,256]
// final h (or null; only on the very last chunk of the top layer).
// ---------------------------------------------------------------------------
__global__ __launch_bounds__(256) void gru_scan(const float* __restrict__ gi,
                                                const float* __restrict__ w4,
                                                const float* __restrict__ bh,
                                                float* __restrict__ hstate,
                                                float* __restrict__ outf,
                                                float* __restrict__ outl,
                                                int steps) {
    const int b = blockIdx.x;
    const int j = threadIdx.x;
    __shared__ __align__(16) float hs[NH];
    hs[j] = hstate[b * NH + j];
    const float bhr = bh[j];
    const float bhz = bh[NH + j];
    const float bhn = bh[2 * NH + j];
    const float4* __restrict__ W = (const float4*)w4;   // index: kq*768 + g
    __syncthreads();

    for (int t = 0; t < steps; ++t) {
        float4 ar = {0, 0, 0, 0}, az = {0, 0, 0, 0}, an = {0, 0, 0, 0};
#pragma unroll 8
        for (int kq = 0; kq < 64; ++kq) {
            const float4 h4 = *(const float4*)&hs[kq << 2];   // LDS broadcast
            const float4 w0 = W[kq * NG + j];
            const float4 w1 = W[kq * NG + NH + j];
            const float4 w2 = W[kq * NG + 2 * NH + j];
            ar.x = fmaf(w0.x, h4.x, ar.x); ar.y = fmaf(w0.y, h4.y, ar.y);
            ar.z = fmaf(w0.z, h4.z, ar.z); ar.w = fmaf(w0.w, h4.w, ar.w);
            az.x = fmaf(w1.x, h4.x, az.x); az.y = fmaf(w1.y, h4.y, az.y);
            az.z = fmaf(w1.z, h4.z, az.z); az.w = fmaf(w1.w, h4.w, az.w);
            an.x = fmaf(w2.x, h4.x, an.x); an.y = fmaf(w2.y, h4.y, an.y);
            an.z = fmaf(w2.z, h4.z, an.z); an.w = fmaf(w2.w, h4.w, an.w);
        }
        const float sr = (ar.x + ar.y) + (ar.z + ar.w);
        const float sz = (az.x + az.y) + (az.z + az.w);
        const float sn = (an.x + an.y) + (an.z + an.w);

        const float* g = gi + ((size_t)t * NB + b) * NG;
        const float hp = hs[j];
        const float r = sigf(g[j] + sr + bhr);
        const float z = sigf(g[NH + j] + sz + bhz);
        const float n = tanhfast(g[2 * NH + j] + r * (sn + bhn));
        const float hn = (1.0f - z) * n + z * hp;

        __syncthreads();            // all reads of hs done
        hs[j] = hn;
        __syncthreads();            // hs updated for next step

        if (outf) outf[((size_t)t * NB + b) * NH + j] = hn;
    }

    hstate[b * NH + j] = hs[j];
    if (outl) outl[b * NH + j] = hs[j];
}

// ---------------------------------------------------------------------------
extern "C" void kernel_launch(void* const* d_in, const int* in_sizes, int n_in,
                              void* d_out, int out_size, void* d_ws, size_t ws_size,
                              hipStream_t stream) {
    const float* x   = (const float*)d_in[0];   // [2048,64,256]
    const float* Wih = (const float*)d_in[1];   // [3,768,256]
    const float* Whh = (const float*)d_in[2];   // [3,768,256]
    const float* bih = (const float*)d_in[3];   // [3,768]
    const float* bhh = (const float*)d_in[4];   // [3,768]
    float* out = (float*)d_out;                 // [64,256]

    // workspace layout (floats) — total 11,124,736 floats = 44.5 MB
    float* w4  = (float*)d_ws;                          // 589,824   (2.4 MB)
    float* hst = w4 + 589824;                           // 49,152    (0.2 MB)
    float* gi  = hst + 49152;                           // 6,291,456 (25.2 MB)
    float* obA = gi + 6291456;                          // 2,097,152 (8.4 MB)
    float* obB = obA + 2097152;                         // 2,097,152 (8.4 MB)

    hipMemsetAsync(hst, 0, (size_t)NL * NB * NH * sizeof(float), stream);
    repack_whh<<<2304, 256, 0, stream>>>(Whh, w4);

    for (int c = 0; c < NCH; ++c) {
        for (int l = 0; l < NL; ++l) {
            const float* A = (l == 0) ? (x + (size_t)c * CHUNK * NB * NH)
                                      : ((l == 1) ? obA : obB);
            gemm_gi<<<dim3(12, CHUNK * NB / 64), 256, 0, stream>>>(
                A, Wih + (size_t)l * NG * NH, bih + (size_t)l * NG, gi);
            float* outf = (l == 0) ? obA : ((l == 1) ? obB : nullptr);
            float* outl = (l == 2 && c == NCH - 1) ? out : nullptr;
            gru_scan<<<64, 256, 0, stream>>>(
                gi, w4 + (size_t)l * 196608, bhh + (size_t)l * NG,
                hst + (size_t)l * NB * NH, outf, outl, CHUNK);
        }
    }
}

// Round 3
// 17715.567 us; speedup vs baseline: 2.3728x; 2.3728x over previous
//
#include <hip/hip_runtime.h>
#include <cstdint>
#include <cstddef>

#define NT 2048   // timesteps
#define NB 64     // batch
#define NH 256    // hidden
#define NG 768    // 3*NH
#define NL 3      // layers
#define CHUNK 128 // timesteps per chunk
#define NCH (NT / CHUNK)

typedef _Float16 h2 __attribute__((ext_vector_type(2)));
union HU { unsigned int u; h2 h; };

__device__ __forceinline__ float sigf(float x) {
    return 1.0f / (1.0f + __expf(-x));
}
__device__ __forceinline__ float tanhfast(float x) {
    float e = __expf(2.0f * x);
    return 1.0f - 2.0f / (e + 1.0f);
}

// 4x fdot2: acc += sum over 8 f16 pairs packed in wv (weights) * hv (h)
__device__ __forceinline__ float dot8(uint4 wv, uint4 hv, float acc) {
#if __has_builtin(__builtin_amdgcn_fdot2)
    HU a, b;
    a.u = wv.x; b.u = hv.x; acc = __builtin_amdgcn_fdot2(a.h, b.h, acc, false);
    a.u = wv.y; b.u = hv.y; acc = __builtin_amdgcn_fdot2(a.h, b.h, acc, false);
    a.u = wv.z; b.u = hv.z; acc = __builtin_amdgcn_fdot2(a.h, b.h, acc, false);
    a.u = wv.w; b.u = hv.w; acc = __builtin_amdgcn_fdot2(a.h, b.h, acc, false);
#else
    HU a, b;
    const unsigned int wu[4] = {wv.x, wv.y, wv.z, wv.w};
    const unsigned int hu[4] = {hv.x, hv.y, hv.z, hv.w};
#pragma unroll
    for (int i = 0; i < 4; ++i) {
        a.u = wu[i]; b.u = hu[i];
        acc = fmaf((float)a.h[0], (float)b.h[0], acc);
        acc = fmaf((float)a.h[1], (float)b.h[1], acc);
    }
#endif
    return acc;
}

// ---------------------------------------------------------------------------
// Repack W_hh[l][row][k] (fp32, row = g*256 + t) into per-thread fp16 chunks:
// wp[(l*96 + g*32 + cc)*256 + t] = halfs of W_hh[l][g*256+t][cc*8 .. cc*8+7]
// so scan-thread t loads its 96 uint4 chunks fully coalesced.
// ---------------------------------------------------------------------------
__global__ void repack_whh(const float* __restrict__ whh, uint4* __restrict__ wp) {
    int idx = blockIdx.x * 256 + threadIdx.x;     // uint4 index, total 73728
    if (idx >= NL * 96 * 256) return;
    int t = idx & 255;
    int c = (idx >> 8) % 96;
    int l = idx / (96 * 256);
    int g = c >> 5, cc = c & 31;
    const float* row = whh + ((size_t)(l * NG + g * NH + t)) * NH + cc * 8;
    HU u0, u1, u2, u3;
    u0.h = h2{(_Float16)row[0], (_Float16)row[1]};
    u1.h = h2{(_Float16)row[2], (_Float16)row[3]};
    u2.h = h2{(_Float16)row[4], (_Float16)row[5]};
    u3.h = h2{(_Float16)row[6], (_Float16)row[7]};
    wp[idx] = uint4{u0.u, u1.u, u2.u, u3.u};
}

// ---------------------------------------------------------------------------
// C[M,768] = A[M,256] @ W[768,256]^T + bias   (fp32, LDS-tiled 64x64x32)
// ---------------------------------------------------------------------------
__global__ __launch_bounds__(256) void gemm_gi(const float* __restrict__ A,
                                               const float* __restrict__ W,
                                               const float* __restrict__ bias,
                                               float* __restrict__ C) {
    __shared__ float As[32][68];
    __shared__ float Bs[32][68];
    const int tid = threadIdx.x;
    const int tx = tid & 15;
    const int ty = tid >> 4;
    const int m0 = blockIdx.y << 6;
    const int n0 = blockIdx.x << 6;
    const int lr = tid >> 2;
    const int lc = tid & 3;

    float acc[4][4] = {{0.0f}};

    for (int kt = 0; kt < 256; kt += 32) {
#pragma unroll
        for (int h = 0; h < 2; ++h) {
            const int c = lc + (h << 2);
            float4 av = *(const float4*)&A[(size_t)(m0 + lr) * 256 + kt + (c << 2)];
            float4 bv = *(const float4*)&W[(size_t)(n0 + lr) * 256 + kt + (c << 2)];
            As[(c << 2) + 0][lr] = av.x; As[(c << 2) + 1][lr] = av.y;
            As[(c << 2) + 2][lr] = av.z; As[(c << 2) + 3][lr] = av.w;
            Bs[(c << 2) + 0][lr] = bv.x; Bs[(c << 2) + 1][lr] = bv.y;
            Bs[(c << 2) + 2][lr] = bv.z; Bs[(c << 2) + 3][lr] = bv.w;
        }
        __syncthreads();
#pragma unroll
        for (int kk = 0; kk < 32; ++kk) {
            float4 a4 = *(const float4*)&As[kk][ty << 2];
            float4 b4 = *(const float4*)&Bs[kk][tx << 2];
            float a[4] = {a4.x, a4.y, a4.z, a4.w};
            float b[4] = {b4.x, b4.y, b4.z, b4.w};
#pragma unroll
            for (int i = 0; i < 4; ++i)
#pragma unroll
                for (int j = 0; j < 4; ++j)
                    acc[i][j] = fmaf(a[i], b[j], acc[i][j]);
        }
        __syncthreads();
    }

    const float4 bv = *(const float4*)&bias[n0 + (tx << 2)];
#pragma unroll
    for (int i = 0; i < 4; ++i) {
        float4 o;
        o.x = acc[i][0] + bv.x;
        o.y = acc[i][1] + bv.y;
        o.z = acc[i][2] + bv.z;
        o.w = acc[i][3] + bv.w;
        *(float4*)&C[(size_t)(m0 + (ty << 2) + i) * NG + n0 + (tx << 2)] = o;
    }
}

// ---------------------------------------------------------------------------
// Register-resident GRU scan. One block per batch element. Thread t owns
// h-column t: weight rows {t, 256+t, 512+t} live as 96 uint4 (384 fp16 pairs)
// in VGPRs. h state: fp32 in a register; fp16 copy broadcast via 512B LDS.
// wp: layer-offset repacked weights. gi: [steps,B,768]. bh: [768].
// hst: [B,256] persistent fp32 state. outf: [steps,B,256] or null.
// ---------------------------------------------------------------------------
__global__ __launch_bounds__(256, 1) void gru_scan(const float* __restrict__ gi,
                                                   const uint4* __restrict__ wp,
                                                   const float* __restrict__ bh,
                                                   float* __restrict__ hst,
                                                   float* __restrict__ outf,
                                                   float* __restrict__ outl,
                                                   int steps) {
    const int b = blockIdx.x;
    const int t = threadIdx.x;
    __shared__ __align__(16) _Float16 hsH[NH];

    // load this thread's 768 weights (96 uint4), fully coalesced
    uint4 w[96];
#pragma unroll
    for (int c = 0; c < 96; ++c) w[c] = wp[c * 256 + t];

    float h = hst[b * NH + t];
    const float bhr = bh[t];
    const float bhz = bh[NH + t];
    const float bhn = bh[2 * NH + t];

    hsH[t] = (_Float16)h;
    __syncthreads();
    const uint4* hs4 = (const uint4*)hsH;

    for (int st = 0; st < steps; ++st) {
        const float* g = gi + ((size_t)st * NB + b) * NG;
        const float gr = g[t];
        const float gz = g[NH + t];
        const float gn = g[2 * NH + t];

        float a0 = 0.0f, a1 = 0.0f, a2 = 0.0f;
#pragma unroll
        for (int cc = 0; cc < 32; ++cc) {
            const uint4 hv = hs4[cc];            // LDS broadcast, conflict-free
            a0 = dot8(w[cc], hv, a0);            // r-gate row
            a1 = dot8(w[32 + cc], hv, a1);       // z-gate row
            a2 = dot8(w[64 + cc], hv, a2);       // n-gate row
        }

        const float r = sigf(gr + a0 + bhr);
        const float z = sigf(gz + a1 + bhz);
        const float n = tanhfast(gn + r * (a2 + bhn));
        h = (1.0f - z) * n + z * h;

        __syncthreads();                         // all reads of hsH done
        hsH[t] = (_Float16)h;
        if (outf) outf[((size_t)st * NB + b) * NH + t] = h;
        __syncthreads();                         // new h visible
    }

    hst[b * NH + t] = h;
    if (outl) outl[b * NH + t] = h;
}

// ---------------------------------------------------------------------------
extern "C" void kernel_launch(void* const* d_in, const int* in_sizes, int n_in,
                              void* d_out, int out_size, void* d_ws, size_t ws_size,
                              hipStream_t stream) {
    const float* x   = (const float*)d_in[0];   // [2048,64,256]
    const float* Wih = (const float*)d_in[1];   // [3,768,256]
    const float* Whh = (const float*)d_in[2];   // [3,768,256]
    const float* bih = (const float*)d_in[3];   // [3,768]
    const float* bhh = (const float*)d_in[4];   // [3,768]
    float* out = (float*)d_out;                 // [64,256]

    // workspace layout — total ~44 MB
    uint4* wpack = (uint4*)d_ws;                        // 73728 uint4 (1.18 MB)
    float* hst = (float*)(wpack + NL * 96 * 256);       // 49,152 f32  (0.2 MB)
    float* gi  = hst + (size_t)NL * NB * NH;            // 6,291,456   (25.2 MB)
    float* obA = gi + (size_t)CHUNK * NB * NG;          // 2,097,152   (8.4 MB)
    float* obB = obA + (size_t)CHUNK * NB * NH;         // 2,097,152   (8.4 MB)

    hipMemsetAsync(hst, 0, (size_t)NL * NB * NH * sizeof(float), stream);
    repack_whh<<<288, 256, 0, stream>>>(Whh, wpack);

    for (int c = 0; c < NCH; ++c) {
        for (int l = 0; l < NL; ++l) {
            const float* A = (l == 0) ? (x + (size_t)c * CHUNK * NB * NH)
                                      : ((l == 1) ? obA : obB);
            gemm_gi<<<dim3(12, CHUNK * NB / 64), 256, 0, stream>>>(
                A, Wih + (size_t)l * NG * NH, bih + (size_t)l * NG, gi);
            float* outf = (l == 0) ? obA : ((l == 1) ? obB : nullptr);
            float* outl = (l == 2 && c == NCH - 1) ? out : nullptr;
            gru_scan<<<NB, 256, 0, stream>>>(
                gi, wpack + (size_t)l * 96 * 256, bhh + (size_t)l * NG,
                hst + (size_t)l * NB * NH, outf, outl, CHUNK);
        }
    }
}

// Round 4
// 10111.765 us; speedup vs baseline: 4.1572x; 1.7520x over previous
//
#include <hip/hip_runtime.h>
#include <cstdint>
#include <cstddef>

#define NT 2048   // timesteps
#define NB 64     // batch
#define NH 256    // hidden
#define NG 768    // 3*NH
#define NL 3      // layers
#define CHUNK 128 // timesteps per chunk
#define NCH (NT / CHUNK)

typedef _Float16 h2 __attribute__((ext_vector_type(2)));
union HU { unsigned int u; h2 h; };

__device__ __forceinline__ float sigf(float x) {
    return 1.0f / (1.0f + __expf(-x));
}
__device__ __forceinline__ float tanhfast(float x) {
    float e = __expf(2.0f * x);
    return 1.0f - 2.0f / (e + 1.0f);
}

// 4x fdot2: acc += sum over 8 f16 pairs packed in wv (weights) * hv (h)
__device__ __forceinline__ float dot8(uint4 wv, uint4 hv, float acc) {
#if __has_builtin(__builtin_amdgcn_fdot2)
    HU a, b;
    a.u = wv.x; b.u = hv.x; acc = __builtin_amdgcn_fdot2(a.h, b.h, acc, false);
    a.u = wv.y; b.u = hv.y; acc = __builtin_amdgcn_fdot2(a.h, b.h, acc, false);
    a.u = wv.z; b.u = hv.z; acc = __builtin_amdgcn_fdot2(a.h, b.h, acc, false);
    a.u = wv.w; b.u = hv.w; acc = __builtin_amdgcn_fdot2(a.h, b.h, acc, false);
#else
    HU a, b;
    const unsigned int wu[4] = {wv.x, wv.y, wv.z, wv.w};
    const unsigned int hu[4] = {hv.x, hv.y, hv.z, hv.w};
#pragma unroll
    for (int i = 0; i < 4; ++i) {
        a.u = wu[i]; b.u = hu[i];
        acc = fmaf((float)a.h[0], (float)b.h[0], acc);
        acc = fmaf((float)a.h[1], (float)b.h[1], acc);
    }
#endif
    return acc;
}

// ---------------------------------------------------------------------------
// Repack W_hh (fp32 [3][768][256]) into per-thread fp16 chunks for the
// 512-thread split-K scan. Thread t owns col=t>>1, khalf=t&1; its chunk
// (g,cc) = W[g*256+col][khalf*128 + cc*8 .. +7], stored at
// wp[l][(g*16+cc)*512 + t] so weight loads are fully coalesced.
// ---------------------------------------------------------------------------
__global__ void repack_whh(const float* __restrict__ whh, uint4* __restrict__ wp) {
    int idx = blockIdx.x * 256 + threadIdx.x;     // uint4 index, total 73728
    if (idx >= NL * 48 * 512) return;
    int t  = idx & 511;
    int c  = (idx >> 9) % 48;
    int l  = idx / (48 * 512);
    int g  = c >> 4, cc = c & 15;
    int col = t >> 1, kh = t & 1;
    const float* row = whh + ((size_t)(l * NG + g * NH + col)) * NH + kh * 128 + cc * 8;
    HU u0, u1, u2, u3;
    u0.h = h2{(_Float16)row[0], (_Float16)row[1]};
    u1.h = h2{(_Float16)row[2], (_Float16)row[3]};
    u2.h = h2{(_Float16)row[4], (_Float16)row[5]};
    u3.h = h2{(_Float16)row[6], (_Float16)row[7]};
    wp[idx] = uint4{u0.u, u1.u, u2.u, u3.u};
}

// ---------------------------------------------------------------------------
// C[M,768] = A[M,256] @ W[768,256]^T + bias   (fp32, LDS-tiled 64x64x32)
// ---------------------------------------------------------------------------
__global__ __launch_bounds__(256) void gemm_gi(const float* __restrict__ A,
                                               const float* __restrict__ W,
                                               const float* __restrict__ bias,
                                               float* __restrict__ C) {
    __shared__ float As[32][68];
    __shared__ float Bs[32][68];
    const int tid = threadIdx.x;
    const int tx = tid & 15;
    const int ty = tid >> 4;
    const int m0 = blockIdx.y << 6;
    const int n0 = blockIdx.x << 6;
    const int lr = tid >> 2;
    const int lc = tid & 3;

    float acc[4][4] = {{0.0f}};

    for (int kt = 0; kt < 256; kt += 32) {
#pragma unroll
        for (int h = 0; h < 2; ++h) {
            const int c = lc + (h << 2);
            float4 av = *(const float4*)&A[(size_t)(m0 + lr) * 256 + kt + (c << 2)];
            float4 bv = *(const float4*)&W[(size_t)(n0 + lr) * 256 + kt + (c << 2)];
            As[(c << 2) + 0][lr] = av.x; As[(c << 2) + 1][lr] = av.y;
            As[(c << 2) + 2][lr] = av.z; As[(c << 2) + 3][lr] = av.w;
            Bs[(c << 2) + 0][lr] = bv.x; Bs[(c << 2) + 1][lr] = bv.y;
            Bs[(c << 2) + 2][lr] = bv.z; Bs[(c << 2) + 3][lr] = bv.w;
        }
        __syncthreads();
#pragma unroll
        for (int kk = 0; kk < 32; ++kk) {
            float4 a4 = *(const float4*)&As[kk][ty << 2];
            float4 b4 = *(const float4*)&Bs[kk][tx << 2];
            float a[4] = {a4.x, a4.y, a4.z, a4.w};
            float b[4] = {b4.x, b4.y, b4.z, b4.w};
#pragma unroll
            for (int i = 0; i < 4; ++i)
#pragma unroll
                for (int j = 0; j < 4; ++j)
                    acc[i][j] = fmaf(a[i], b[j], acc[i][j]);
        }
        __syncthreads();
    }

    const float4 bv = *(const float4*)&bias[n0 + (tx << 2)];
#pragma unroll
    for (int i = 0; i < 4; ++i) {
        float4 o;
        o.x = acc[i][0] + bv.x;
        o.y = acc[i][1] + bv.y;
        o.z = acc[i][2] + bv.z;
        o.w = acc[i][3] + bv.w;
        *(float4*)&C[(size_t)(m0 + (ty << 2) + i) * NG + n0 + (tx << 2)] = o;
    }
}

// ---------------------------------------------------------------------------
// Split-K register-resident GRU scan. 512 threads/block, one block per batch
// element. Thread t owns output col = t>>1 and K-half kh = t&1: 48 uint4
// (192 VGPRs) of fp16 weights. Partner lanes (t, t^1) hold the two K-halves
// -> full dot via __shfl_xor(.,1). h: fp32 in register (col owner), fp16
// double-buffered broadcast copy in LDS. One barrier per step.
// ---------------------------------------------------------------------------
__global__ __launch_bounds__(512, 2) void gru_scan(const float* __restrict__ gi,
                                                   const uint4* __restrict__ wp,
                                                   const float* __restrict__ bh,
                                                   float* __restrict__ hst,
                                                   float* __restrict__ outf,
                                                   float* __restrict__ outl,
                                                   int steps) {
    const int b   = blockIdx.x;
    const int t   = threadIdx.x;
    const int col = t >> 1;
    const int kh  = t & 1;
    const bool own = (kh == 0);
    __shared__ __align__(16) _Float16 hsH[2][NH];

    // load this thread's 48 weight chunks, fully coalesced
    uint4 w[48];
#pragma unroll
    for (int c = 0; c < 48; ++c) w[c] = wp[c * 512 + t];

    float h = hst[b * NH + col];
    const float bhr = bh[col];
    const float bhz = bh[NH + col];
    const float bhn = bh[2 * NH + col];

    if (own) hsH[0][col] = (_Float16)h;
    __syncthreads();

    // preload gi for step 0
    const float* g0 = gi + (size_t)b * NG;
    float gr = g0[col], gz = g0[NH + col], gn = g0[2 * NH + col];

    int p = 0;
    for (int st = 0; st < steps; ++st) {
        // prefetch next step's input gates (hidden under the dot phase)
        const int stq = (st + 1 < steps) ? (st + 1) : st;
        const float* gq = gi + ((size_t)stq * NB + b) * NG;
        const float pr = gq[col], pz = gq[NH + col], pn = gq[2 * NH + col];

        const uint4* hv = (const uint4*)&hsH[p][kh << 7];   // my K-half (16 uint4)
        float a0 = 0.0f, a1 = 0.0f, a2 = 0.0f;
#pragma unroll
        for (int cc = 0; cc < 16; ++cc) {
            const uint4 hh = hv[cc];
            a0 = dot8(w[cc],      hh, a0);   // r row, my half
            a1 = dot8(w[16 + cc], hh, a1);   // z row
            a2 = dot8(w[32 + cc], hh, a2);   // n row
        }
        // combine K-halves with the partner lane (both lanes get full sums)
        a0 += __shfl_xor(a0, 1);
        a1 += __shfl_xor(a1, 1);
        a2 += __shfl_xor(a2, 1);

        const float r = sigf(gr + a0 + bhr);
        const float z = sigf(gz + a1 + bhz);
        const float n = tanhfast(gn + r * (a2 + bhn));
        h = (1.0f - z) * n + z * h;

        if (own) {
            hsH[p ^ 1][col] = (_Float16)h;   // write other buffer: no WAR hazard
            if (outf) outf[((size_t)st * NB + b) * NH + col] = h;
        }
        gr = pr; gz = pz; gn = pn;
        p ^= 1;
        __syncthreads();                     // new h visible; old buffer free
    }

    if (own) {
        hst[b * NH + col] = h;
        if (outl) outl[b * NH + col] = h;
    }
}

// ---------------------------------------------------------------------------
extern "C" void kernel_launch(void* const* d_in, const int* in_sizes, int n_in,
                              void* d_out, int out_size, void* d_ws, size_t ws_size,
                              hipStream_t stream) {
    const float* x   = (const float*)d_in[0];   // [2048,64,256]
    const float* Wih = (const float*)d_in[1];   // [3,768,256]
    const float* Whh = (const float*)d_in[2];   // [3,768,256]
    const float* bih = (const float*)d_in[3];   // [3,768]
    const float* bhh = (const float*)d_in[4];   // [3,768]
    float* out = (float*)d_out;                 // [64,256]

    // workspace layout — total ~44 MB
    uint4* wpack = (uint4*)d_ws;                        // 73728 uint4 (1.18 MB)
    float* hst = (float*)(wpack + NL * 48 * 512);       // 49,152 f32  (0.2 MB)
    float* gi  = hst + (size_t)NL * NB * NH;            // 6,291,456   (25.2 MB)
    float* obA = gi + (size_t)CHUNK * NB * NG;          // 2,097,152   (8.4 MB)
    float* obB = obA + (size_t)CHUNK * NB * NH;         // 2,097,152   (8.4 MB)

    hipMemsetAsync(hst, 0, (size_t)NL * NB * NH * sizeof(float), stream);
    repack_whh<<<288, 256, 0, stream>>>(Whh, wpack);

    for (int c = 0; c < NCH; ++c) {
        for (int l = 0; l < NL; ++l) {
            const float* A = (l == 0) ? (x + (size_t)c * CHUNK * NB * NH)
                                      : ((l == 1) ? obA : obB);
            gemm_gi<<<dim3(12, CHUNK * NB / 64), 256, 0, stream>>>(
                A, Wih + (size_t)l * NG * NH, bih + (size_t)l * NG, gi);
            float* outf = (l == 0) ? obA : ((l == 1) ? obB : nullptr);
            float* outl = (l == 2 && c == NCH - 1) ? out : nullptr;
            gru_scan<<<NB, 512, 0, stream>>>(
                gi, wpack + (size_t)l * 48 * 512, bhh + (size_t)l * NG,
                hst + (size_t)l * NB * NH, outf, outl, CHUNK);
        }
    }
}